// Round 4
// baseline (994.812 us; speedup 1.0000x reference)
//
#include <hip/hip_runtime.h>

typedef __attribute__((ext_vector_type(8))) short short8;
typedef __attribute__((ext_vector_type(4))) float floatx4;

__device__ __forceinline__ float bf2f(short s) {
    unsigned u = ((unsigned)(unsigned short)s) << 16;
    return __builtin_bit_cast(float, u);
}
__device__ __forceinline__ short f2bf(float x) {
    unsigned u = __builtin_bit_cast(unsigned, x);
    u = (u + 0x7FFFu + ((u >> 16) & 1u)) >> 16;   // RNE
    return (short)u;
}

// Transpose edge weights (K,128)->(128,K) into bf16 so MFMA B-fragments are
// contiguous 16B loads: B[k][n] = wT[n*K + k].
__global__ __launch_bounds__(256) void prep_weights(
    const float* ew1, const float* ew2, short* ew1T, short* ew2T)
{
    int idx = blockIdx.x * 256 + threadIdx.x;
    if (idx < 49152) {               // edge_w1 (384,128)
        int k = idx >> 7, n = idx & 127;
        ew1T[n * 384 + k] = f2bf(ew1[idx]);
    } else if (idx < 65536) {        // edge_w2 (128,128)
        int i = idx - 49152; int k = i >> 7, n = i & 127;
        ew2T[n * 128 + k] = f2bf(ew2[i]);
    }
}

__global__ __launch_bounds__(256) void scatter_add_kernel(
    const float* ef, const int* recv, float* agg, long total)
{
    long idx = (long)blockIdx.x * 256 + threadIdx.x;
    if (idx < total) {
        int e = (int)(idx >> 7), c = (int)(idx & 127);
        atomicAdd(agg + (size_t)recv[e] * 128 + c, ef[idx]);
    }
}

// Node MLP + LN, exact f32 VALU path (matches np f32 reference closely).
// Block = 256 threads = 8 rows x 32 threads; each thread owns 4 output cols.
__global__ __launch_bounds__(256) void node_mlp_valu(
    const float* node_f, const float* agg,
    const float* w1, const float* b1, const float* w2, const float* b2,
    const float* g, const float* bvec,
    float* out, int N)
{
    const int r = threadIdx.x >> 5;
    const int sub = threadIdx.x & 31;
    const int row = blockIdx.x * 8 + r;
    const int c0 = sub * 4;

    __shared__ float xs[8][256];
    __shared__ float hs[8][128];

    for (int i = threadIdx.x; i < 2048; i += 256) {
        int rr = i >> 8, k = i & 255;
        size_t grow = (size_t)blockIdx.x * 8 + rr;
        if (grow >= (size_t)N) grow = N - 1;
        xs[rr][k] = (k < 128) ? node_f[grow * 128 + k]
                              : agg[grow * 128 + (k - 128)];
    }
    __syncthreads();

    float acc[4] = {0.f, 0.f, 0.f, 0.f};
    for (int k = 0; k < 256; k++) {
        float xv = xs[r][k];
        floatx4 w = *reinterpret_cast<const floatx4*>(w1 + (size_t)k * 128 + c0);
#pragma unroll
        for (int j = 0; j < 4; j++) acc[j] += xv * w[j];
    }
#pragma unroll
    for (int j = 0; j < 4; j++)
        hs[r][c0 + j] = acc[j] + b1[c0 + j];
    __syncthreads();

    float acc2[4] = {0.f, 0.f, 0.f, 0.f};
    for (int k = 0; k < 128; k++) {
        float hv = hs[r][k];
        floatx4 w = *reinterpret_cast<const floatx4*>(w2 + (size_t)k * 128 + c0);
#pragma unroll
        for (int j = 0; j < 4; j++) acc2[j] += hv * w[j];
    }

    float v4[4]; float s1 = 0.f, s2 = 0.f;
#pragma unroll
    for (int j = 0; j < 4; j++) {
        float v = acc2[j] + b2[c0 + j];
        v4[j] = v; s1 += v; s2 += v * v;
    }
#pragma unroll
    for (int off = 1; off < 32; off <<= 1) {
        s1 += __shfl_xor(s1, off, 32);
        s2 += __shfl_xor(s2, off, 32);
    }
    if (row < N) {
        const float mu = s1 * (1.f / 128.f);
        const float var = s2 * (1.f / 128.f) - mu * mu;
        const float rstd = rsqrtf(var + 1e-5f);
        floatx4 o;
#pragma unroll
        for (int j = 0; j < 4; j++)
            o[j] = (v4[j] - mu) * rstd * g[c0 + j] + bvec[c0 + j];
        *reinterpret_cast<floatx4*>(out + (size_t)row * 128 + c0) = o;
    }
}

// Edge MLP + LN via MFMA 16x16x32 bf16 (f32 in/out, bf16 internal).
// A row = [nodes[senders[e]] | nodes[receivers[e]] | edge_features(e)], K1=384.
__global__ __launch_bounds__(256) void edge_mlp_mfma(
    const float* feat, const float* nodes,
    const int* senders, const int* receivers,
    const short* w1T, const short* w2T,
    const float* b1, const float* b2, const float* g, const float* bvec,
    float* out, int nrows)
{
    const int wave = threadIdx.x >> 6;
    const int lane = threadIdx.x & 63;
    const int m = lane & 15;        // A-row / C-col within tile
    const int quad = lane >> 4;     // k-group / C-row-group

    const int row0 = blockIdx.x * 64 + wave * 16;
    const bool active = (row0 < nrows);      // nrows % 16 == 0 -> whole waves valid
    int row = row0 + m;
    if (row >= nrows) row = nrows - 1;       // clamp for safe loads

    const int s_idx = senders[row];
    const int r_idx = receivers[row];

    const floatx4 zero4 = {0.f, 0.f, 0.f, 0.f};
    floatx4 acc1[8];
#pragma unroll
    for (int t = 0; t < 8; t++) acc1[t] = zero4;

    for (int ks = 0; ks < 12; ks++) {
        const int k0 = ks * 32 + quad * 8;
        const float* p;
        if (k0 < 128)       p = nodes + (size_t)s_idx * 128 + k0;
        else if (k0 < 256)  p = nodes + (size_t)r_idx * 128 + (k0 - 128);
        else                p = feat  + (size_t)row   * 128 + (k0 - 256);
        floatx4 f0 = *reinterpret_cast<const floatx4*>(p);
        floatx4 f1 = *reinterpret_cast<const floatx4*>(p + 4);
        short8 a;
#pragma unroll
        for (int j = 0; j < 4; j++) { a[j] = f2bf(f0[j]); a[4 + j] = f2bf(f1[j]); }
#pragma unroll
        for (int t = 0; t < 8; t++) {
            short8 b = *reinterpret_cast<const short8*>(w1T + (size_t)(t * 16 + m) * 384 + k0);
            acc1[t] = __builtin_amdgcn_mfma_f32_16x16x32_bf16(a, b, acc1[t], 0, 0, 0);
        }
    }

    // h = layer1 + b1 -> LDS (bf16): C-layout -> A-layout round trip
    __shared__ short lds_h[4][16][136];
#pragma unroll
    for (int t = 0; t < 8; t++) {
        const int col = t * 16 + m;
        const float bias = b1[col];
#pragma unroll
        for (int r = 0; r < 4; r++)
            lds_h[wave][quad * 4 + r][col] = f2bf(acc1[t][r] + bias);
    }
    __syncthreads();

    floatx4 acc2[8];
#pragma unroll
    for (int t = 0; t < 8; t++) acc2[t] = zero4;
#pragma unroll
    for (int ks = 0; ks < 4; ks++) {
        const int k0 = ks * 32 + quad * 8;
        short8 a = *reinterpret_cast<const short8*>(&lds_h[wave][m][k0]);
#pragma unroll
        for (int t = 0; t < 8; t++) {
            short8 b = *reinterpret_cast<const short8*>(w2T + (size_t)(t * 16 + m) * 128 + k0);
            acc2[t] = __builtin_amdgcn_mfma_f32_16x16x32_bf16(a, b, acc2[t], 0, 0, 0);
        }
    }

    // bias2 + LayerNorm over each row's 128 cols
    float vals[8][4];
    float s1[4] = {0.f, 0.f, 0.f, 0.f}, s2[4] = {0.f, 0.f, 0.f, 0.f};
#pragma unroll
    for (int t = 0; t < 8; t++) {
        const float bias = b2[t * 16 + m];
#pragma unroll
        for (int r = 0; r < 4; r++) {
            float v = acc2[t][r] + bias;
            vals[t][r] = v; s1[r] += v; s2[r] += v * v;
        }
    }
#pragma unroll
    for (int off = 1; off < 16; off <<= 1) {
#pragma unroll
        for (int r = 0; r < 4; r++) {
            s1[r] += __shfl_xor(s1[r], off);
            s2[r] += __shfl_xor(s2[r], off);
        }
    }
    if (active) {
#pragma unroll
        for (int r = 0; r < 4; r++) {
            const float mu = s1[r] * (1.f / 128.f);
            const float var = s2[r] * (1.f / 128.f) - mu * mu;
            const float rstd = rsqrtf(var + 1e-5f);
            const int orow = row0 + quad * 4 + r;
#pragma unroll
            for (int t = 0; t < 8; t++) {
                const int col = t * 16 + m;
                out[(size_t)orow * 128 + col] =
                    (vals[t][r] - mu) * rstd * g[col] + bvec[col];
            }
        }
    }
}

extern "C" void kernel_launch(void* const* d_in, const int* in_sizes, int n_in,
                              void* d_out, int out_size, void* d_ws, size_t ws_size,
                              hipStream_t stream)
{
    const float* node_f = (const float*)d_in[0];
    const float* edge_f = (const float*)d_in[1];
    const int* senders   = (const int*)d_in[2];
    const int* receivers = (const int*)d_in[3];
    const float* nw1 = (const float*)d_in[4];
    const float* nb1 = (const float*)d_in[5];
    const float* nw2 = (const float*)d_in[6];
    const float* nb2 = (const float*)d_in[7];
    const float* ng  = (const float*)d_in[8];
    const float* nbb = (const float*)d_in[9];
    const float* ew1 = (const float*)d_in[10];
    const float* eb1 = (const float*)d_in[11];
    const float* ew2 = (const float*)d_in[12];
    const float* eb2 = (const float*)d_in[13];
    const float* eg  = (const float*)d_in[14];
    const float* ebb = (const float*)d_in[15];

    const int N = in_sizes[0] / 128;
    const int E = in_sizes[2];

    // ws: agg (N*128 f32) + transposed bf16 edge weights (~130 KB). ~25.8 MB
    // total — proven in-budget (rounds 2/3 behaved identically with agg here
    // vs in d_out).
    char* ws = (char*)d_ws;
    float* agg  = (float*)ws;
    short* ew1T = (short*)(ws + (size_t)N * 512);
    short* ew2T = (short*)(ws + (size_t)N * 512 + 98304);

    float* out_nodes = (float*)d_out;
    float* out_edges = out_nodes + (size_t)N * 128;

    hipMemsetAsync(agg, 0, (size_t)N * 512, stream);
    prep_weights<<<256, 256, 0, stream>>>(ew1, ew2, ew1T, ew2T);

    const long total = (long)E * 128;
    scatter_add_kernel<<<(int)((total + 255) / 256), 256, 0, stream>>>(
        edge_f, receivers, agg, total);

    node_mlp_valu<<<(N + 7) / 8, 256, 0, stream>>>(
        node_f, agg, nw1, nb1, nw2, nb2, ng, nbb, out_nodes, N);

    edge_mlp_mfma<<<(E + 63) / 64, 256, 0, stream>>>(
        edge_f, out_nodes, senders, receivers,
        ew1T, ew2T, eb1, eb2, eg, ebb, out_edges, E);
}